// Round 1
// baseline (712.118 us; speedup 1.0000x reference)
//
#include <hip/hip_runtime.h>
#include <hip/hip_bf16.h>

// TrendEncoder: histogram (B=4096 rows, S=200 events -> 256 bins) + 256-step
// LSTM (input_size=1, H=64) returning final hidden state [B, 64].
//
// Fully fused: one block = NB(=4) batch rows, 256 threads.
//   phase 0: device-side dtype probe (bf16 vs f32 inputs) per block
//   phase 1: histogram into LDS x_sh[NB][256] (float atomics, exact ints)
//   phase 2: LSTM. thread j = gate row j holds W_hh[j][0..63] in VGPRs;
//            h lives in LDS (broadcast float4 reads), gates exchanged via LDS,
//            thread j doubles as unit (b'=j>>6, k'=j&63) holding c in a reg.

#define B_S   200   // history length
#define B_H   64    // LSTM hidden
#define B_T   256   // time bins / LSTM steps
#define B_NB  4     // batch rows per block

__device__ __forceinline__ float load_f(const void* p, int i, int isb) {
    if (isb) return __bfloat162float(((const __hip_bfloat16*)p)[i]);
    return ((const float*)p)[i];
}

__global__ __launch_bounds__(256)
void trend_encoder_kernel(const void* __restrict__ time_,
                          const int*  __restrict__ length,
                          const void* __restrict__ ptime_,
                          const void* __restrict__ wih_,
                          const void* __restrict__ whh_,
                          const void* __restrict__ bih_,
                          const void* __restrict__ bhh_,
                          void* __restrict__ out_) {
    __shared__ __align__(16) float x_sh[B_NB][B_T];     // histogram / LSTM input
    __shared__ __align__(16) float h_sh[B_NB][B_H];     // hidden state
    __shared__ __align__(16) float g_sh[B_NB][4 * B_H]; // gate exchange
    __shared__ int flag_sh;

    const int j  = threadIdx.x;        // gate row 0..255
    const int b0 = blockIdx.x * B_NB;  // first batch row of this block

    // ---- dtype probe: W_ih ~ uniform(-0.125, 0.125). If the buffer is f32,
    // its low 16-bit halves decode to wild bf16 values -> flag=0.
    if (j == 0) {
        const unsigned short* u = (const unsigned short*)wih_;
        int ok = 1;
        for (int i = 0; i < 256; ++i) {
            float v = __uint_as_float(((unsigned int)u[i]) << 16);
            if (!(v > -0.2f && v < 0.2f)) { ok = 0; break; }  // NaN also fails
        }
        flag_sh = ok;
    }
    // zero the histogram
    #pragma unroll
    for (int b = 0; b < B_NB; ++b) x_sh[b][j] = 0.0f;
    __syncthreads();
    const int isb = flag_sh;

    // ---- histogram: pos = trunc((pt - t) * 0.25); add at bin 255-pos.
    // (x/4.0f == x*0.25f exactly; trunc-toward-zero matches astype(int32).)
    for (int b = 0; b < B_NB; ++b) {
        const int row = b0 + b;
        const float pt = load_f(ptime_, row, isb);
        const int len  = length[row];
        if (j < B_S && j < len) {
            float tv = load_f(time_, row * B_S + j, isb);
            int pos = (int)((pt - tv) * 0.25f);
            if (pos >= 0 && pos < B_T) atomicAdd(&x_sh[b][B_T - 1 - pos], 1.0f);
        }
    }

    // ---- per-thread weights (gate row j)
    float w[B_H];
    #pragma unroll
    for (int k = 0; k < B_H; ++k) w[k] = load_f(whh_, j * B_H + k, isb);
    const float wih  = load_f(wih_, j, isb);
    const float bias = load_f(bih_, j, isb) + load_f(bhh_, j, isb);

    // unit owned by this thread for the c/h update
    const int bp = j >> 6, kp = j & 63;
    float c_reg = 0.0f, h_last = 0.0f;
    h_sh[bp][kp] = 0.0f;
    __syncthreads();   // hist atomics + h init visible

    for (int t = 0; t < B_T; ++t) {
        // phase A: gates = x_t*W_ih + h @ W_hh^T + b   (reads h_sh, writes g_sh)
        #pragma unroll
        for (int b = 0; b < B_NB; ++b) {
            float a = fmaf(x_sh[b][t], wih, bias);
            #pragma unroll
            for (int k = 0; k < B_H; k += 4) {
                float4 hv = *(const float4*)&h_sh[b][k];  // broadcast read
                a = fmaf(hv.x, w[k + 0], a);
                a = fmaf(hv.y, w[k + 1], a);
                a = fmaf(hv.z, w[k + 2], a);
                a = fmaf(hv.w, w[k + 3], a);
            }
            g_sh[b][j] = a;
        }
        __syncthreads();

        // phase B: c,h update for unit (bp,kp)  (reads g_sh, writes h_sh)
        const float gi = g_sh[bp][kp];
        const float gf = g_sh[bp][kp + 64];
        const float gg = g_sh[bp][kp + 128];
        const float go = g_sh[bp][kp + 192];
        const float si = 1.0f / (1.0f + expf(-gi));
        const float sf = 1.0f / (1.0f + expf(-gf));
        const float sg = tanhf(gg);
        const float so = 1.0f / (1.0f + expf(-go));
        c_reg  = fmaf(sf, c_reg, si * sg);
        h_last = so * tanhf(c_reg);
        h_sh[bp][kp] = h_last;
        __syncthreads();
    }

    // ---- epilogue: final h for unit (bp,kp)
    const int o = (b0 + bp) * B_H + kp;
    if (isb) ((__hip_bfloat16*)out_)[o] = __float2bfloat16(h_last);
    else     ((float*)out_)[o] = h_last;
}

extern "C" void kernel_launch(void* const* d_in, const int* in_sizes, int n_in,
                              void* d_out, int out_size, void* d_ws, size_t ws_size,
                              hipStream_t stream) {
    const void* time_  = d_in[0];              // [B, 200]  bf16 (or f32)
    const int*  length = (const int*)d_in[1];  // [B]       int32
    const void* ptime  = d_in[2];              // [B]       bf16 (or f32)
    const void* wih    = d_in[3];              // [256]     bf16 (or f32)
    const void* whh    = d_in[4];              // [256,64]  bf16 (or f32)
    const void* bih    = d_in[5];              // [256]     bf16 (or f32)
    const void* bhh    = d_in[6];              // [256]     bf16 (or f32)

    const int B = in_sizes[1];                 // 4096
    trend_encoder_kernel<<<dim3(B / B_NB), dim3(256), 0, stream>>>(
        time_, length, ptime, wih, whh, bih, bhh, d_out);
}

// Round 2
// 267.385 us; speedup vs baseline: 2.6633x; 2.6633x over previous
//
#include <hip/hip_runtime.h>
#include <hip/hip_bf16.h>

// TrendEncoder: histogram (B=4096, S=200 -> 256 bins) + 256-step LSTM (H=64),
// MFMA edition.
//
// Block = 16 batch rows, 512 threads (8 waves). Per step:
//   G[16x256] = Hhi@Wt + Hlo@Wt + x_t*W_ih + b   via mfma_f32_16x16x32_bf16
//   wave w owns gate-cols 32w..32w+31 (2 16x16 tiles, K=64 in 2 chunks,
//   hi/lo split -> 8 MFMA/wave/step). W-fragments resident in VGPRs.
//   h lives in LDS as bf16 hi/lo, row-major stride 72 (A-frag = ds_read_b128).
//   Gates exchanged via LDS (stride 260); thread owns 2 adjacent h-units,
//   keeps c in registers, writes h back as packed 2xbf16 dwords.

#define B_S     200
#define B_T     256
#define ROWS    16
#define THREADS 512
#define XS      257   // x_sh row stride (floats)
#define GS      260   // g_sh row stride (floats)
#define HS      72    // h row stride (bf16 elems) = 144 B

typedef __attribute__((ext_vector_type(8))) short short8;
typedef __attribute__((ext_vector_type(4))) float float4_t;

__device__ __forceinline__ float load_f(const void* p, int i, int isb) {
    if (isb) {
        unsigned short u = ((const unsigned short*)p)[i];
        return __uint_as_float(((unsigned int)u) << 16);
    }
    return ((const float*)p)[i];
}

__device__ __forceinline__ unsigned short f2bf(float x) {
    unsigned int u = __float_as_uint(x);
    u += 0x7fffu + ((u >> 16) & 1u);          // round-to-nearest-even
    return (unsigned short)(u >> 16);
}

__device__ __forceinline__ float fast_sigmoid(float x) {
    float e = __builtin_amdgcn_exp2f(-x * 1.4426950408889634f);
    return __builtin_amdgcn_rcpf(1.0f + e);
}
__device__ __forceinline__ float fast_tanh(float x) {
    float e = __builtin_amdgcn_exp2f(x * 2.8853900817779268f);
    return 1.0f - 2.0f * __builtin_amdgcn_rcpf(1.0f + e);
}

__global__ __launch_bounds__(THREADS)
void trend_encoder_kernel(const void* __restrict__ time_,
                          const int*  __restrict__ length,
                          const void* __restrict__ ptime_,
                          const void* __restrict__ wih_,
                          const void* __restrict__ whh_,
                          const void* __restrict__ bih_,
                          const void* __restrict__ bhh_,
                          void* __restrict__ out_) {
    __shared__ __align__(16) float x_sh[ROWS * XS];
    __shared__ __align__(16) float g_sh[ROWS * GS];
    __shared__ __align__(16) unsigned short h_hi[ROWS * HS];
    __shared__ __align__(16) unsigned short h_lo[ROWS * HS];
    __shared__ int flag_sh;

    const int tid  = threadIdx.x;
    const int wv   = tid >> 6;        // wave 0..7 -> gate-col strip 32*wv
    const int lane = tid & 63;
    const int m    = lane & 15;       // MFMA row (A) / col (B,C)
    const int quad = lane >> 4;       // MFMA quad
    const int b0   = blockIdx.x * ROWS;

    // ---- dtype probe (wave 0): W_ih ~ U(-0.125,0.125); f32 reinterpreted as
    // bf16 words goes out of range with overwhelming probability.
    if (tid < 64) {
        unsigned short u = ((const unsigned short*)wih_)[tid];
        float v = __uint_as_float(((unsigned int)u) << 16);
        int bad = !(v > -0.2f && v < 0.2f);
        unsigned long long bm = __ballot(bad);
        if (lane == 0) flag_sh = (bm == 0ULL) ? 1 : 0;
    }
    for (int i = tid; i < ROWS * XS; i += THREADS) x_sh[i] = 0.0f;
    for (int i = tid; i < ROWS * HS; i += THREADS) { h_hi[i] = 0; h_lo[i] = 0; }
    __syncthreads();
    const int isb = flag_sh;

    // ---- histogram: pos = trunc((pt - t)*0.25), add at bin 255-pos
    for (int e = tid; e < ROWS * B_S; e += THREADS) {
        int row  = e / B_S;
        int s    = e - row * B_S;
        int grow = b0 + row;
        if (s < length[grow]) {
            float pt = load_f(ptime_, grow, isb);
            float tv = load_f(time_, grow * B_S + s, isb);
            int pos = (int)((pt - tv) * 0.25f);
            if (pos >= 0 && pos < B_T)
                atomicAdd(&x_sh[row * XS + (B_T - 1 - pos)], 1.0f);
        }
    }

    // ---- resident B fragments: Wt[k][n] = W_hh[n][k], n = 32*wv + 16*t + m,
    // chunk c covers k = 32c + 8*quad + j  (B-frag layout: n=lane&15, k=quad*8+j)
    const int n0 = wv * 32;
    short8 bw[2][2];
    float wihv[2], biasv[2];
    #pragma unroll
    for (int t = 0; t < 2; ++t) {
        int n = n0 + 16 * t + m;
        wihv[t]  = load_f(wih_, n, isb);
        biasv[t] = load_f(bih_, n, isb) + load_f(bhh_, n, isb);
        #pragma unroll
        for (int c = 0; c < 2; ++c) {
            short8 v;
            #pragma unroll
            for (int j = 0; j < 8; ++j)
                v[j] = (short)f2bf(load_f(whh_, n * 64 + 32 * c + 8 * quad + j, isb));
            bw[t][c] = v;
        }
    }

    // ---- per-thread activation ownership: 2 adjacent units
    const int arow = tid >> 5;          // 0..15
    const int hp   = (tid & 31) * 2;    // 0,2,..,62
    float c0 = 0.0f, c1 = 0.0f, h0 = 0.0f, h1 = 0.0f;
    __syncthreads();   // histogram + h init visible

    for (int t = 0; t < B_T; ++t) {
        // A fragments: A[m][k=quad*8+j], hi/lo, 2 K-chunks (ds_read_b128)
        short8 ahi0 = *(const short8*)&h_hi[m * HS +      8 * quad];
        short8 ahi1 = *(const short8*)&h_hi[m * HS + 32 + 8 * quad];
        short8 alo0 = *(const short8*)&h_lo[m * HS +      8 * quad];
        short8 alo1 = *(const short8*)&h_lo[m * HS + 32 + 8 * quad];
        // C init: x[row][t]*W_ih[n] + bias[n]; C/D row = quad*4+reg, col = m
        float xv[4];
        #pragma unroll
        for (int r = 0; r < 4; ++r) xv[r] = x_sh[(quad * 4 + r) * XS + t];
        float4_t acc[2];
        #pragma unroll
        for (int tt = 0; tt < 2; ++tt) {
            float4_t a;
            #pragma unroll
            for (int r = 0; r < 4; ++r) a[r] = fmaf(xv[r], wihv[tt], biasv[tt]);
            a = __builtin_amdgcn_mfma_f32_16x16x32_bf16(ahi0, bw[tt][0], a, 0, 0, 0);
            a = __builtin_amdgcn_mfma_f32_16x16x32_bf16(alo0, bw[tt][0], a, 0, 0, 0);
            a = __builtin_amdgcn_mfma_f32_16x16x32_bf16(ahi1, bw[tt][1], a, 0, 0, 0);
            a = __builtin_amdgcn_mfma_f32_16x16x32_bf16(alo1, bw[tt][1], a, 0, 0, 0);
            acc[tt] = a;
        }
        // scatter G to LDS
        #pragma unroll
        for (int tt = 0; tt < 2; ++tt)
            #pragma unroll
            for (int r = 0; r < 4; ++r)
                g_sh[(quad * 4 + r) * GS + n0 + 16 * tt + m] = acc[tt][r];
        __syncthreads();

        // activation for units (arow, hp) and (arow, hp+1)
        const float* gr = &g_sh[arow * GS + hp];
        float gi0 = gr[0],   gi1 = gr[1];
        float gf0 = gr[64],  gf1 = gr[65];
        float gg0 = gr[128], gg1 = gr[129];
        float go0 = gr[192], go1 = gr[193];
        c0 = fmaf(fast_sigmoid(gf0), c0, fast_sigmoid(gi0) * fast_tanh(gg0));
        c1 = fmaf(fast_sigmoid(gf1), c1, fast_sigmoid(gi1) * fast_tanh(gg1));
        h0 = fast_sigmoid(go0) * fast_tanh(c0);
        h1 = fast_sigmoid(go1) * fast_tanh(c1);
        // h -> bf16 hi + lo residual, packed 2-unit dword stores
        unsigned int b_hi0 = f2bf(h0), b_hi1 = f2bf(h1);
        float r0 = h0 - __uint_as_float(b_hi0 << 16);
        float r1 = h1 - __uint_as_float(b_hi1 << 16);
        unsigned int hiw = b_hi0 | (b_hi1 << 16);
        unsigned int low = (unsigned int)f2bf(r0) | ((unsigned int)f2bf(r1) << 16);
        *(unsigned int*)&h_hi[arow * HS + hp] = hiw;
        *(unsigned int*)&h_lo[arow * HS + hp] = low;
        __syncthreads();
    }

    // ---- epilogue: final h of the 2 owned units
    const int o = (b0 + arow) * 64 + hp;
    if (isb) {
        ((__hip_bfloat16*)out_)[o]     = __float2bfloat16(h0);
        ((__hip_bfloat16*)out_)[o + 1] = __float2bfloat16(h1);
    } else {
        ((float*)out_)[o]     = h0;
        ((float*)out_)[o + 1] = h1;
    }
}

extern "C" void kernel_launch(void* const* d_in, const int* in_sizes, int n_in,
                              void* d_out, int out_size, void* d_ws, size_t ws_size,
                              hipStream_t stream) {
    const void* time_  = d_in[0];
    const int*  length = (const int*)d_in[1];
    const void* ptime  = d_in[2];
    const void* wih    = d_in[3];
    const void* whh    = d_in[4];
    const void* bih    = d_in[5];
    const void* bhh    = d_in[6];

    const int B = in_sizes[1];   // 4096
    trend_encoder_kernel<<<dim3(B / ROWS), dim3(THREADS), 0, stream>>>(
        time_, length, ptime, wih, whh, bih, bhh, d_out);
}

// Round 3
// 240.286 us; speedup vs baseline: 2.9636x; 1.1128x over previous
//
#include <hip/hip_runtime.h>
#include <hip/hip_bf16.h>

// TrendEncoder: histogram (B=4096, S=200 -> 256 bins) + 256-step LSTM (H=64).
// Round 3: gate-aligned wave tiling — in-lane activation, 1 barrier/step.
//
// Block = 16 batch rows, 256 threads (4 waves), 1 block/CU (grid 256).
// Wave wv owns gate-col tiles {16wv, 16wv+64, 16wv+128, 16wv+192} = tiles
// tt=0..3 = gates i,f,g,o. After mfma_f32_16x16x32_bf16, lane (quad,m) holds
// all 4 gates of units (row=quad*4+r, col=16wv+m) in registers -> activation
// entirely in-lane (c in VGPRs, no gate LDS exchange). h round-trips through
// double-buffered LDS (bf16 hi + lo residual for fp32-class accuracy);
// exactly one __syncthreads per step. x stored transposed [t][row] so the
// C-init read is one broadcast ds_read_b128.

#define B_S     200
#define B_T     256
#define ROWS    16
#define THREADS 256
#define HS      72    // h row stride (bf16 elems) = 144 B

typedef __attribute__((ext_vector_type(8))) short short8;
typedef __attribute__((ext_vector_type(4))) float float4_t;

__device__ __forceinline__ float load_f(const void* p, int i, int isb) {
    if (isb) {
        unsigned short u = ((const unsigned short*)p)[i];
        return __uint_as_float(((unsigned int)u) << 16);
    }
    return ((const float*)p)[i];
}

__device__ __forceinline__ unsigned short f2bf(float x) {
    unsigned int u = __float_as_uint(x);
    u += 0x7fffu + ((u >> 16) & 1u);          // round-to-nearest-even
    return (unsigned short)(u >> 16);
}

__device__ __forceinline__ float fast_sigmoid(float x) {
    float e = __builtin_amdgcn_exp2f(-x * 1.4426950408889634f);
    return __builtin_amdgcn_rcpf(1.0f + e);
}
__device__ __forceinline__ float fast_tanh(float x) {
    float e = __builtin_amdgcn_exp2f(x * 2.8853900817779268f);
    return 1.0f - 2.0f * __builtin_amdgcn_rcpf(1.0f + e);
}

__global__ __launch_bounds__(THREADS)
void trend_encoder_kernel(const void* __restrict__ time_,
                          const int*  __restrict__ length,
                          const void* __restrict__ ptime_,
                          const void* __restrict__ wih_,
                          const void* __restrict__ whh_,
                          const void* __restrict__ bih_,
                          const void* __restrict__ bhh_,
                          void* __restrict__ out_) {
    __shared__ __align__(16) float x_t[B_T * ROWS];              // [t][row], 16 KB
    __shared__ __align__(16) unsigned short h_hi[2][ROWS * HS];  // double-buffered
    __shared__ __align__(16) unsigned short h_lo[2][ROWS * HS];
    __shared__ int flag_sh;

    const int tid  = threadIdx.x;
    const int wv   = tid >> 6;        // wave 0..3
    const int lane = tid & 63;
    const int m    = lane & 15;
    const int quad = lane >> 4;
    const int b0   = blockIdx.x * ROWS;

    // ---- dtype probe (wave 0): W_ih ~ U(-0.125,0.125); f32 reinterpreted as
    // bf16 words goes far out of range with overwhelming probability.
    if (tid < 64) {
        unsigned short u = ((const unsigned short*)wih_)[tid];
        float v = __uint_as_float(((unsigned int)u) << 16);
        int bad = !(v > -0.2f && v < 0.2f);
        unsigned long long bm = __ballot(bad);
        if (lane == 0) flag_sh = (bm == 0ULL) ? 1 : 0;
    }
    for (int i = tid; i < B_T * ROWS; i += THREADS) x_t[i] = 0.0f;
    for (int i = tid; i < ROWS * HS; i += THREADS) { h_hi[0][i] = 0; h_lo[0][i] = 0; }
    __syncthreads();
    const int isb = flag_sh;

    // ---- histogram: pos = trunc((pt - t)*0.25), add at bin 255-pos (transposed)
    for (int e = tid; e < ROWS * B_S; e += THREADS) {
        int row  = e / B_S;
        int s    = e - row * B_S;
        int grow = b0 + row;
        if (s < length[grow]) {
            float pt = load_f(ptime_, grow, isb);
            float tv = load_f(time_, grow * B_S + s, isb);
            int pos = (int)((pt - tv) * 0.25f);
            if (pos >= 0 && pos < B_T)
                atomicAdd(&x_t[(B_T - 1 - pos) * ROWS + row], 1.0f);
        }
    }

    // ---- resident weights: tile tt = gate tt (i,f,g,o), col n = 16wv + 64tt + m
    // B-frag layout: n = lane&15, k = 32c + 8*quad + j
    short8 bw[4][2];
    float wihv[4], biasv[4];
    #pragma unroll
    for (int tt = 0; tt < 4; ++tt) {
        int n = 16 * wv + 64 * tt + m;
        wihv[tt]  = load_f(wih_, n, isb);
        biasv[tt] = load_f(bih_, n, isb) + load_f(bhh_, n, isb);
        #pragma unroll
        for (int c = 0; c < 2; ++c) {
            short8 v;
            #pragma unroll
            for (int j = 0; j < 8; ++j)
                v[j] = (short)f2bf(load_f(whh_, n * 64 + 32 * c + 8 * quad + j, isb));
            bw[tt][c] = v;
        }
    }

    const int aoff = m * HS + 8 * quad;   // A-frag base (elems)
    const int kcol = 16 * wv + m;         // owned unit column
    float creg[4] = {0.f, 0.f, 0.f, 0.f};
    float hreg[4] = {0.f, 0.f, 0.f, 0.f};
    __syncthreads();   // histogram + h init + weights visible

    for (int t = 0; t < B_T; ++t) {
        const int p = t & 1;
        // A fragments (A[m][k], m=lane&15, k=8*quad+j): hi/lo x 2 K-chunks
        const unsigned short* hh = h_hi[p];
        const unsigned short* hl = h_lo[p];
        short8 ahi0 = *(const short8*)&hh[aoff];
        short8 ahi1 = *(const short8*)&hh[aoff + 32];
        short8 alo0 = *(const short8*)&hl[aoff];
        short8 alo1 = *(const short8*)&hl[aoff + 32];
        // x broadcast: rows quad*4..quad*4+3 of step t, one b128
        float4_t xv = *(const float4_t*)&x_t[t * ROWS + quad * 4];

        float4_t acc[4];
        #pragma unroll
        for (int tt = 0; tt < 4; ++tt) {
            float4_t a;
            #pragma unroll
            for (int r = 0; r < 4; ++r) a[r] = fmaf(xv[r], wihv[tt], biasv[tt]);
            a = __builtin_amdgcn_mfma_f32_16x16x32_bf16(ahi0, bw[tt][0], a, 0, 0, 0);
            a = __builtin_amdgcn_mfma_f32_16x16x32_bf16(alo0, bw[tt][0], a, 0, 0, 0);
            a = __builtin_amdgcn_mfma_f32_16x16x32_bf16(ahi1, bw[tt][1], a, 0, 0, 0);
            a = __builtin_amdgcn_mfma_f32_16x16x32_bf16(alo1, bw[tt][1], a, 0, 0, 0);
            acc[tt] = a;
        }

        // in-lane activation: 4 units (row = quad*4+r, col = kcol)
        unsigned short* whi = h_hi[p ^ 1];
        unsigned short* wlo = h_lo[p ^ 1];
        #pragma unroll
        for (int r = 0; r < 4; ++r) {
            float gi = acc[0][r], gf = acc[1][r], gg = acc[2][r], go = acc[3][r];
            creg[r] = fmaf(fast_sigmoid(gf), creg[r], fast_sigmoid(gi) * fast_tanh(gg));
            float h = fast_sigmoid(go) * fast_tanh(creg[r]);
            hreg[r] = h;
            unsigned short bh = f2bf(h);
            float res = h - __uint_as_float(((unsigned int)bh) << 16);
            whi[(quad * 4 + r) * HS + kcol] = bh;
            wlo[(quad * 4 + r) * HS + kcol] = f2bf(res);
        }
        __syncthreads();   // the only barrier per step
    }

    // ---- epilogue: final h of the 4 owned units
    #pragma unroll
    for (int r = 0; r < 4; ++r) {
        int o = (b0 + quad * 4 + r) * 64 + kcol;
        if (isb) ((__hip_bfloat16*)out_)[o] = __float2bfloat16(hreg[r]);
        else     ((float*)out_)[o] = hreg[r];
    }
}

extern "C" void kernel_launch(void* const* d_in, const int* in_sizes, int n_in,
                              void* d_out, int out_size, void* d_ws, size_t ws_size,
                              hipStream_t stream) {
    const void* time_  = d_in[0];
    const int*  length = (const int*)d_in[1];
    const void* ptime  = d_in[2];
    const void* wih    = d_in[3];
    const void* whh    = d_in[4];
    const void* bih    = d_in[5];
    const void* bhh    = d_in[6];

    const int B = in_sizes[1];   // 4096
    trend_encoder_kernel<<<dim3(B / ROWS), dim3(THREADS), 0, stream>>>(
        time_, length, ptime, wih, whh, bih, bhh, d_out);
}